// Round 11
// baseline (187.020 us; speedup 1.0000x reference)
//
#include <hip/hip_runtime.h>

// MultiHeadSelfAttention2D: B=8, C=128, H=W=64, N=4096, heads=4, hd=32
// Pipeline: prep (transpose x -> tokens bf16, weights -> bf16; Wq pre-scaled
//                 by 1/sqrt(32)*log2(e) so QK^T lands in the exp2 domain)
//           proj3 (QKV via MFMA; V written PRE-FRAGMENTED per kv-block so the
//                  attn B-operand is a single 16B load per lane)
//           attn  (flash attention, 4-way split-KV, MAX-FREE softmax,
//                  single-buffer loads, P packed via NATIVE __bf16 casts ->
//                  compiler emits v_cvt_pk_bf16_f32 (m240: scalar cast beats
//                  hand asm; asm-union pack was the R7/R9 miscompile),
//                  XCD swizzle, LDS merge)
//           projo (output projection, transposed store)

using f32x4  = __attribute__((ext_vector_type(4))) float;
using bf16x8 = __attribute__((ext_vector_type(8))) short;   // MFMA operand (4 VGPRs)
using bfv8   = __attribute__((ext_vector_type(8))) __bf16;  // native bf16 vector

#define QSCALE 0.17677669529663687f  // 1/sqrt(32)
#define LOG2E  1.4426950408889634f
#define QKS    (QSCALE * LOG2E)      // folded into Wq/bq -> S = logit*log2e

static __device__ __forceinline__ unsigned short f2bf(float f) {
    union { float f; unsigned int u; } v; v.f = f;
    unsigned int r = v.u + 0x7FFFu + ((v.u >> 16) & 1u);  // RNE
    return (unsigned short)(r >> 16);
}

static __device__ __forceinline__ f32x4 mfma16(bf16x8 a, bf16x8 b, f32x4 c) {
    return __builtin_amdgcn_mfma_f32_16x16x32_bf16(a, b, c, 0, 0, 0);
}

// ---------------------------------------------------------------------------
// prep: x (B,128,4096) f32 -> t_bf (B,4096,128) bf16 ; weights f32 -> bf16
__global__ __launch_bounds__(256) void k_prep(
    const float* __restrict__ x,
    const float* __restrict__ Wq, const float* __restrict__ Wk,
    const float* __restrict__ Wv, const float* __restrict__ Wo,
    unsigned short* __restrict__ t_bf, unsigned short* __restrict__ Wb)
{
    const int bx = blockIdx.x;
    const int tid = threadIdx.x;
    if (bx >= 1024) {
        const int m = bx - 1024;
        const float* W = (m == 0) ? Wq : (m == 1) ? Wk : (m == 2) ? Wv : Wo;
        const float s = (m == 0) ? QKS : 1.0f;
        for (int idx = tid; idx < 16384; idx += 256)
            Wb[m * 16384 + idx] = f2bf(W[idx] * s);
        return;
    }
    __shared__ float tl[64][65];  // +1 pad: conflict-free transpose
    const int b  = bx >> 7;
    const int c0 = ((bx >> 6) & 1) * 64;
    const int n0 = (bx & 63) * 64;
    for (int idx = tid; idx < 4096; idx += 256) {
        const int ci = idx >> 6, nj = idx & 63;
        tl[ci][nj] = x[((size_t)(b * 128 + c0 + ci)) * 4096 + n0 + nj];
    }
    __syncthreads();
    for (int idx = tid; idx < 4096; idx += 256) {
        const int nj = idx >> 6, ci = idx & 63;
        t_bf[((size_t)(b * 4096 + n0 + nj)) * 128 + c0 + ci] = f2bf(tl[ci][nj]);
    }
}

// ---------------------------------------------------------------------------
// proj3: Q/K/V = t @ W^T + b.   grid (512, 3): 64 tokens/block, blockIdx.y=mat.
// Q,K stored (bh, n, 32) bf16 (Q pre-scaled by QKS).
// V stored per kv-block as a 2KB tile [32 rows d][32 kv], with each row's kv
// order pre-fragmented: row position 8*g + 4*hi + lo  <->  kv = 16*hi + 4*g + lo.
// Lane (g,l15) of the attn PV B-frag then reads ONE 16B chunk at byte 16*g.
__global__ __launch_bounds__(256) void k_proj3(
    const unsigned short* __restrict__ t_bf, const unsigned short* __restrict__ Wb,
    const float* __restrict__ bq, const float* __restrict__ bk, const float* __restrict__ bv,
    unsigned short* __restrict__ Qb, unsigned short* __restrict__ Kb,
    unsigned short* __restrict__ Vt)
{
    const int mat  = blockIdx.y;
    const int widx = threadIdx.x >> 6;
    const int lane = threadIdx.x & 63;
    const int g = lane >> 4, l15 = lane & 15;
    const int row0 = blockIdx.x * 64 + widx * 16;
    const int gt_row = row0 + l15;
    const unsigned short* Wm = Wb + mat * 16384;
    const float* bias = (mat == 0) ? bq : (mat == 1) ? bk : bv;

    bf16x8 tf[4];
    #pragma unroll
    for (int kc = 0; kc < 4; ++kc)
        tf[kc] = *(const bf16x8*)(t_bf + (size_t)gt_row * 128 + kc * 32 + g * 8);

    #pragma unroll
    for (int ot = 0; ot < 8; ++ot) {
        f32x4 acc;
        if (mat < 2) {
            float bb = bias[ot * 16 + l15];
            if (mat == 0) bb *= QKS;
            acc[0] = bb; acc[1] = bb; acc[2] = bb; acc[3] = bb;
        } else {
            #pragma unroll
            for (int r = 0; r < 4; ++r) acc[r] = bias[ot * 16 + 4 * g + r];
        }
        #pragma unroll
        for (int kc = 0; kc < 4; ++kc) {
            bf16x8 wf = *(const bf16x8*)(Wm + (size_t)(ot * 16 + l15) * 128 + kc * 32 + g * 8);
            acc = (mat == 2) ? mfma16(wf, tf[kc], acc) : mfma16(tf[kc], wf, acc);
        }
        if (mat < 2) {
            unsigned short* dst = (mat == 0) ? Qb : Kb;
            const int o = ot * 16 + l15, h = o >> 5, d = o & 31;
            #pragma unroll
            for (int r = 0; r < 4; ++r) {
                const int gt = row0 + 4 * g + r;
                const int b = gt >> 12, n = gt & 4095;
                dst[(((size_t)(b * 4 + h)) * 4096 + n) * 32 + d] = f2bf(acc[r]);
            }
        } else {
            const int b = gt_row >> 12, n = gt_row & 4095;
            const int n31 = n & 31;
            // pre-fragmented position within the 32-wide row
            const int pos = ((n31 >> 2) & 3) * 8 + ((n31 >> 4) & 1) * 4 + (n31 & 3);
            #pragma unroll
            for (int r = 0; r < 4; ++r) {
                const int o = ot * 16 + 4 * g + r, h2 = o >> 5, d = o & 31;
                const size_t tb2 = ((size_t)(b * 4 + h2) * 128 + ((n >> 5) & 127)) * 1024;
                Vt[tb2 + d * 32 + pos] = f2bf(acc[r]);
            }
        }
    }
}

// ---------------------------------------------------------------------------
// attn: flash attention, 4-way split-KV, MAX-FREE. Block = 4 waves = 1 q-tile
// x 4 KV quarters. Wave widx: 32 q rows, KV in [widx*1024, widx*1024+1024).
// Swapped QK^T: mfma(K,Q) -> lane(g,l15) reg r = S[q=l15][kv0(+16)+4g+r], where
// S is already logit*log2e (QKS folded into Wq) -> p = exp2(S) directly.
// P packed in-register into PV A-frag with slot map pi(g,j)=16*(j>>2)+4g+(j&3);
// V B-frag is ONE 16B load thanks to the pre-fragmented Vt layout (same map).
// Denominator = extra PV MFMA against constant-1.0 B operand (acc2*).
// P packing via NATIVE __bf16 casts (fptrunc -> v_cvt_pk_bf16_f32, RNE,
// bit-identical to f2bf) — no inline asm, no integer bit-twiddling.
// Quarters merged through LDS by plain addition, wave 0 writes.
__global__ __launch_bounds__(256) void k_attn(
    const unsigned short* __restrict__ Qb, const unsigned short* __restrict__ Kb,
    const unsigned short* __restrict__ Vt, unsigned short* __restrict__ Ob)
{
    // bijective XCD swizzle (4096 blocks % 8 == 0): XCD x gets a contiguous
    // 512-block chunk -> 4 bh (1 MB K/V) working set per XCD L2.
    const int bid = blockIdx.x;
    const int swz = (bid & 7) * 512 + (bid >> 3);
    const int widx = threadIdx.x >> 6;           // KV quarter 0..3
    const int bh = swz >> 7, q0 = (swz & 127) * 32;
    const int lane = threadIdx.x & 63, g = lane >> 4, l15 = lane & 15;

    __shared__ float lacc[3][32][36];   // [writer][col d][row q], padded
    __shared__ float lden[3][32];       // [writer][row q]

    const bf16x8 qf0 = *(const bf16x8*)(Qb + ((size_t)bh * 4096 + q0 + l15) * 32 + g * 8);
    const bf16x8 qf1 = *(const bf16x8*)(Qb + ((size_t)bh * 4096 + q0 + 16 + l15) * 32 + g * 8);

    // K pointer: row (widx*1024 + l15), element g*8.  +1024 elems per 32-kv tile.
    const unsigned short* kp = Kb + (size_t)bh * 131072
                             + (size_t)(widx * 1024 + l15) * 32 + g * 8;
    // V pointer: quarter base, row d=l15, fragment chunk g (16B).
    const unsigned short* vp = Vt + (size_t)bh * 131072 + (size_t)widx * 32768
                             + l15 * 32 + g * 8;

    bf16x8 onesf;
    #pragma unroll
    for (int j = 0; j < 8; ++j) onesf[j] = (short)0x3F80;  // bf16 1.0

    f32x4 acc00 = {0.f,0.f,0.f,0.f}, acc01 = {0.f,0.f,0.f,0.f};
    f32x4 acc10 = {0.f,0.f,0.f,0.f}, acc11 = {0.f,0.f,0.f,0.f};
    f32x4 acc20 = {0.f,0.f,0.f,0.f}, acc21 = {0.f,0.f,0.f,0.f};
    const f32x4 z = {0.f,0.f,0.f,0.f};

    #pragma unroll 2
    for (int it = 0; it < 32; ++it) {
        const bf16x8 kf0 = *(const bf16x8*)(kp);
        const bf16x8 kf1 = *(const bf16x8*)(kp + 512);   // rows +16
        const bf16x8 vf0 = *(const bf16x8*)(vp);         // d = l15
        const bf16x8 vf1 = *(const bf16x8*)(vp + 512);   // d = 16 + l15
        kp += 1024;
        vp += 1024;

        f32x4 s00 = mfma16(kf0, qf0, z), s01 = mfma16(kf1, qf0, z);
        f32x4 s10 = mfma16(kf0, qf1, z), s11 = mfma16(kf1, qf1, z);

        bfv8 pb0, pb1;
        #pragma unroll
        for (int i = 0; i < 4; ++i) {
            pb0[i]     = (__bf16)__builtin_amdgcn_exp2f(s00[i]);
            pb0[4 + i] = (__bf16)__builtin_amdgcn_exp2f(s01[i]);
            pb1[i]     = (__bf16)__builtin_amdgcn_exp2f(s10[i]);
            pb1[4 + i] = (__bf16)__builtin_amdgcn_exp2f(s11[i]);
        }
        const bf16x8 pa0 = __builtin_bit_cast(bf16x8, pb0);
        const bf16x8 pa1 = __builtin_bit_cast(bf16x8, pb1);

        acc00 = mfma16(pa0, vf0, acc00);   // rows q0..+15,  O cols 0..15
        acc01 = mfma16(pa0, vf1, acc01);   //                O cols 16..31
        acc20 = mfma16(pa0, onesf, acc20); // denominator rows q0..+15
        acc10 = mfma16(pa1, vf0, acc10);   // rows q0+16..+31
        acc11 = mfma16(pa1, vf1, acc11);
        acc21 = mfma16(pa1, onesf, acc21);
    }

    // ---- merge the four quarters (plain addition; no max state) ------------
    if (widx != 0) {
        const int s = widx - 1;
        *(f32x4*)&lacc[s][l15][4 * g]           = acc00;  // [col][row]
        *(f32x4*)&lacc[s][16 + l15][4 * g]      = acc01;
        *(f32x4*)&lacc[s][l15][16 + 4 * g]      = acc10;
        *(f32x4*)&lacc[s][16 + l15][16 + 4 * g] = acc11;
        if (l15 == 0) {
            #pragma unroll
            for (int r = 0; r < 4; ++r) {
                lden[s][4 * g + r]      = acc20[r];
                lden[s][16 + 4 * g + r] = acc21[r];
            }
        }
    }
    __syncthreads();
    if (widx != 0) return;

    const int b = bh >> 2, h = bh & 3;
    #pragma unroll
    for (int r = 0; r < 4; ++r) {
        const int row0 = 4 * g + r, row1 = 16 + 4 * g + r;
        const float rd0 = 1.0f / (acc20[r] + lden[0][row0] + lden[1][row0] + lden[2][row0]);
        const float rd1 = 1.0f / (acc21[r] + lden[0][row1] + lden[1][row1] + lden[2][row1]);
        const float o00 = acc00[r] + lacc[0][l15][row0]      + lacc[1][l15][row0]      + lacc[2][l15][row0];
        const float o01 = acc01[r] + lacc[0][16 + l15][row0] + lacc[1][16 + l15][row0] + lacc[2][16 + l15][row0];
        const float o10 = acc10[r] + lacc[0][l15][row1]      + lacc[1][l15][row1]      + lacc[2][l15][row1];
        const float o11 = acc11[r] + lacc[0][16 + l15][row1] + lacc[1][16 + l15][row1] + lacc[2][16 + l15][row1];
        const size_t base0 = ((size_t)b * 4096 + q0 + row0) * 128 + h * 32;
        const size_t base1 = ((size_t)b * 4096 + q0 + row1) * 128 + h * 32;
        Ob[base0 + l15]      = f2bf(o00 * rd0);
        Ob[base0 + 16 + l15] = f2bf(o01 * rd0);
        Ob[base1 + l15]      = f2bf(o10 * rd1);
        Ob[base1 + 16 + l15] = f2bf(o11 * rd1);
    }
}

// ---------------------------------------------------------------------------
// projo: out(b,c,n) = (O @ Wo^T + bo)^T via swapped MFMA (A=Wo rows, B=O rows)
__global__ __launch_bounds__(256) void k_projo(
    const unsigned short* __restrict__ Ob, const unsigned short* __restrict__ Wob,
    const float* __restrict__ bo, float* __restrict__ out)
{
    const int widx = threadIdx.x >> 6;
    const int lane = threadIdx.x & 63, g = lane >> 4, l15 = lane & 15;
    const int gt = blockIdx.x * 64 + widx * 16 + l15;  // token (col of D)
    const int b = gt >> 12, n = gt & 4095;

    bf16x8 of[4];
    #pragma unroll
    for (int kc = 0; kc < 4; ++kc)
        of[kc] = *(const bf16x8*)(Ob + (size_t)gt * 128 + kc * 32 + g * 8);

    #pragma unroll
    for (int ot = 0; ot < 8; ++ot) {
        f32x4 acc;
        #pragma unroll
        for (int r = 0; r < 4; ++r) acc[r] = bo[ot * 16 + 4 * g + r];
        #pragma unroll
        for (int kc = 0; kc < 4; ++kc) {
            bf16x8 wf = *(const bf16x8*)(Wob + (size_t)(ot * 16 + l15) * 128 + kc * 32 + g * 8);
            acc = mfma16(wf, of[kc], acc);
        }
        #pragma unroll
        for (int r = 0; r < 4; ++r)
            out[((size_t)b * 128 + ot * 16 + 4 * g + r) * 4096 + n] = acc[r];
    }
}

// ---------------------------------------------------------------------------
extern "C" void kernel_launch(void* const* d_in, const int* in_sizes, int n_in,
                              void* d_out, int out_size, void* d_ws, size_t ws_size,
                              hipStream_t stream)
{
    const float* x  = (const float*)d_in[0];
    const float* Wq = (const float*)d_in[1];
    const float* bq = (const float*)d_in[2];
    const float* Wk = (const float*)d_in[3];
    const float* bk = (const float*)d_in[4];
    const float* Wv = (const float*)d_in[5];
    const float* bv = (const float*)d_in[6];
    const float* Wo = (const float*)d_in[7];
    const float* bo = (const float*)d_in[8];
    float* out = (float*)d_out;

    char* ws = (char*)d_ws;
    unsigned short* t_bf = (unsigned short*)(ws);             //  8,388,608 B
    unsigned short* Wb   = (unsigned short*)(ws +  8388608);  //    131,072 B
    unsigned short* Qb   = (unsigned short*)(ws +  8519680);  //  8,388,608 B
    unsigned short* Kb   = (unsigned short*)(ws + 16908288);  //  8,388,608 B
    unsigned short* Vt   = (unsigned short*)(ws + 25296896);  //  8,388,608 B
    unsigned short* Ob   = (unsigned short*)(ws + 33685504);  //  8,388,608 B -> 42.1 MB total

    k_prep <<<dim3(1028),     dim3(256), 0, stream>>>(x, Wq, Wk, Wv, Wo, t_bf, Wb);
    k_proj3<<<dim3(512, 3),   dim3(256), 0, stream>>>(t_bf, Wb, bq, bk, bv, Qb, Kb, Vt);
    k_attn <<<dim3(4096),     dim3(256), 0, stream>>>(Qb, Kb, Vt, Ob);
    k_projo<<<dim3(512),      dim3(256), 0, stream>>>(Ob, Wb + 3 * 16384, bo, out);
}

// Round 12
// 173.864 us; speedup vs baseline: 1.0757x; 1.0757x over previous
//
#include <hip/hip_runtime.h>

// MultiHeadSelfAttention2D: B=8, C=128, H=W=64, N=4096, heads=4, hd=32
// Pipeline: prep (transpose x -> tokens bf16, weights -> bf16; Wq pre-scaled
//                 by 1/sqrt(32)*log2(e) so QK^T lands in the exp2 domain)
//           proj3 (QKV via MFMA; V written PRE-FRAGMENTED per kv-block so the
//                  attn B-operand is a single 16B load per lane)
//           attn  (flash attention, 64 q-rows/wave (4 Q-frags: K/V reuse x2,
//                  20 MFMA per load-step), 4-way split-KV, MAX-FREE softmax,
//                  native __bf16 pack, XCD swizzle, LDS merge)
//           projo (output projection, transposed store)

using f32x4  = __attribute__((ext_vector_type(4))) float;
using bf16x8 = __attribute__((ext_vector_type(8))) short;   // MFMA operand (4 VGPRs)
using bfv8   = __attribute__((ext_vector_type(8))) __bf16;  // native bf16 vector

#define QSCALE 0.17677669529663687f  // 1/sqrt(32)
#define LOG2E  1.4426950408889634f
#define QKS    (QSCALE * LOG2E)      // folded into Wq/bq -> S = logit*log2e

static __device__ __forceinline__ unsigned short f2bf(float f) {
    union { float f; unsigned int u; } v; v.f = f;
    unsigned int r = v.u + 0x7FFFu + ((v.u >> 16) & 1u);  // RNE
    return (unsigned short)(r >> 16);
}

static __device__ __forceinline__ f32x4 mfma16(bf16x8 a, bf16x8 b, f32x4 c) {
    return __builtin_amdgcn_mfma_f32_16x16x32_bf16(a, b, c, 0, 0, 0);
}

// ---------------------------------------------------------------------------
// prep: x (B,128,4096) f32 -> t_bf (B,4096,128) bf16 ; weights f32 -> bf16
__global__ __launch_bounds__(256) void k_prep(
    const float* __restrict__ x,
    const float* __restrict__ Wq, const float* __restrict__ Wk,
    const float* __restrict__ Wv, const float* __restrict__ Wo,
    unsigned short* __restrict__ t_bf, unsigned short* __restrict__ Wb)
{
    const int bx = blockIdx.x;
    const int tid = threadIdx.x;
    if (bx >= 1024) {
        const int m = bx - 1024;
        const float* W = (m == 0) ? Wq : (m == 1) ? Wk : (m == 2) ? Wv : Wo;
        const float s = (m == 0) ? QKS : 1.0f;
        for (int idx = tid; idx < 16384; idx += 256)
            Wb[m * 16384 + idx] = f2bf(W[idx] * s);
        return;
    }
    __shared__ float tl[64][65];  // +1 pad: conflict-free transpose
    const int b  = bx >> 7;
    const int c0 = ((bx >> 6) & 1) * 64;
    const int n0 = (bx & 63) * 64;
    for (int idx = tid; idx < 4096; idx += 256) {
        const int ci = idx >> 6, nj = idx & 63;
        tl[ci][nj] = x[((size_t)(b * 128 + c0 + ci)) * 4096 + n0 + nj];
    }
    __syncthreads();
    for (int idx = tid; idx < 4096; idx += 256) {
        const int nj = idx >> 6, ci = idx & 63;
        t_bf[((size_t)(b * 4096 + n0 + nj)) * 128 + c0 + ci] = f2bf(tl[ci][nj]);
    }
}

// ---------------------------------------------------------------------------
// proj3: Q/K/V = t @ W^T + b.   grid (512, 3): 64 tokens/block, blockIdx.y=mat.
// Q,K stored (bh, n, 32) bf16 (Q pre-scaled by QKS).
// V stored per kv-block as a 2KB tile [32 rows d][32 kv], with each row's kv
// order pre-fragmented: row position 8*g + 4*hi + lo  <->  kv = 16*hi + 4*g + lo.
// Lane (g,l15) of the attn PV B-frag then reads ONE 16B chunk at byte 16*g.
__global__ __launch_bounds__(256) void k_proj3(
    const unsigned short* __restrict__ t_bf, const unsigned short* __restrict__ Wb,
    const float* __restrict__ bq, const float* __restrict__ bk, const float* __restrict__ bv,
    unsigned short* __restrict__ Qb, unsigned short* __restrict__ Kb,
    unsigned short* __restrict__ Vt)
{
    const int mat  = blockIdx.y;
    const int widx = threadIdx.x >> 6;
    const int lane = threadIdx.x & 63;
    const int g = lane >> 4, l15 = lane & 15;
    const int row0 = blockIdx.x * 64 + widx * 16;
    const int gt_row = row0 + l15;
    const unsigned short* Wm = Wb + mat * 16384;
    const float* bias = (mat == 0) ? bq : (mat == 1) ? bk : bv;

    bf16x8 tf[4];
    #pragma unroll
    for (int kc = 0; kc < 4; ++kc)
        tf[kc] = *(const bf16x8*)(t_bf + (size_t)gt_row * 128 + kc * 32 + g * 8);

    #pragma unroll
    for (int ot = 0; ot < 8; ++ot) {
        f32x4 acc;
        if (mat < 2) {
            float bb = bias[ot * 16 + l15];
            if (mat == 0) bb *= QKS;
            acc[0] = bb; acc[1] = bb; acc[2] = bb; acc[3] = bb;
        } else {
            #pragma unroll
            for (int r = 0; r < 4; ++r) acc[r] = bias[ot * 16 + 4 * g + r];
        }
        #pragma unroll
        for (int kc = 0; kc < 4; ++kc) {
            bf16x8 wf = *(const bf16x8*)(Wm + (size_t)(ot * 16 + l15) * 128 + kc * 32 + g * 8);
            acc = (mat == 2) ? mfma16(wf, tf[kc], acc) : mfma16(tf[kc], wf, acc);
        }
        if (mat < 2) {
            unsigned short* dst = (mat == 0) ? Qb : Kb;
            const int o = ot * 16 + l15, h = o >> 5, d = o & 31;
            #pragma unroll
            for (int r = 0; r < 4; ++r) {
                const int gt = row0 + 4 * g + r;
                const int b = gt >> 12, n = gt & 4095;
                dst[(((size_t)(b * 4 + h)) * 4096 + n) * 32 + d] = f2bf(acc[r]);
            }
        } else {
            const int b = gt_row >> 12, n = gt_row & 4095;
            const int n31 = n & 31;
            // pre-fragmented position within the 32-wide row
            const int pos = ((n31 >> 2) & 3) * 8 + ((n31 >> 4) & 1) * 4 + (n31 & 3);
            #pragma unroll
            for (int r = 0; r < 4; ++r) {
                const int o = ot * 16 + 4 * g + r, h2 = o >> 5, d = o & 31;
                const size_t tb2 = ((size_t)(b * 4 + h2) * 128 + ((n >> 5) & 127)) * 1024;
                Vt[tb2 + d * 32 + pos] = f2bf(acc[r]);
            }
        }
    }
}

// ---------------------------------------------------------------------------
// attn: flash attention, 4-way split-KV, MAX-FREE. Block = 4 waves = 1 q-tile
// (64 rows) x 4 KV quarters. Wave widx: KV in [widx*1024, widx*1024+1024).
// Each wave holds 4 Q-frags (rows q0+f*16..+15) -> one K/V load feeds
// 8 QK + 12 PV MFMAs (2x reuse vs 32-row waves; halves load-latency exposures).
// Swapped QK^T: mfma(K,Q) -> lane(g,l15) reg r = S[q=f*16+l15][kv0(+16)+4g+r];
// S is already logit*log2e (QKS folded into Wq) -> p = exp2(S) directly.
// P packed via native __bf16 casts (v_cvt_pk_bf16_f32; asm pack = R7/R9 bug).
// V B-frag is ONE 16B load (pre-fragmented Vt, same slot map as P).
// Denominator = extra PV MFMA against constant-1.0 B operand.
// Quarters merged through LDS by plain addition, wave 0 writes.
__global__ __launch_bounds__(256) void k_attn(
    const unsigned short* __restrict__ Qb, const unsigned short* __restrict__ Kb,
    const unsigned short* __restrict__ Vt, unsigned short* __restrict__ Ob)
{
    // bijective XCD swizzle (2048 blocks % 8 == 0): XCD x gets a contiguous
    // 256-block chunk -> 4 bh (1 MB K/V) working set per XCD L2.
    const int bid = blockIdx.x;
    const int swz = (bid & 7) * 256 + (bid >> 3);
    const int widx = threadIdx.x >> 6;           // KV quarter 0..3
    const int bh = swz >> 6, q0 = (swz & 63) * 64;
    const int lane = threadIdx.x & 63, g = lane >> 4, l15 = lane & 15;

    __shared__ float lacc[3][32][68];   // [writer][col d][row q], padded
    __shared__ float lden[3][64];       // [writer][row q]

    bf16x8 qf[4];
    #pragma unroll
    for (int f = 0; f < 4; ++f)
        qf[f] = *(const bf16x8*)(Qb + ((size_t)bh * 4096 + q0 + f * 16 + l15) * 32 + g * 8);

    // K pointer: row (widx*1024 + l15), element g*8.  +1024 elems per 32-kv tile.
    const unsigned short* kp = Kb + (size_t)bh * 131072
                             + (size_t)(widx * 1024 + l15) * 32 + g * 8;
    // V pointer: quarter base, row d=l15, fragment chunk g (16B).
    const unsigned short* vp = Vt + (size_t)bh * 131072 + (size_t)widx * 32768
                             + l15 * 32 + g * 8;

    bf16x8 onesf;
    #pragma unroll
    for (int j = 0; j < 8; ++j) onesf[j] = (short)0x3F80;  // bf16 1.0

    f32x4 aO[4][2];   // [q-frag][O col-half]
    f32x4 aD[4];      // [q-frag] denominator
    #pragma unroll
    for (int f = 0; f < 4; ++f) {
        aO[f][0] = f32x4{0.f,0.f,0.f,0.f};
        aO[f][1] = f32x4{0.f,0.f,0.f,0.f};
        aD[f]    = f32x4{0.f,0.f,0.f,0.f};
    }
    const f32x4 z = {0.f,0.f,0.f,0.f};

    for (int it = 0; it < 32; ++it) {
        const bf16x8 kf0 = *(const bf16x8*)(kp);
        const bf16x8 kf1 = *(const bf16x8*)(kp + 512);   // rows +16
        const bf16x8 vf0 = *(const bf16x8*)(vp);         // d = l15
        const bf16x8 vf1 = *(const bf16x8*)(vp + 512);   // d = 16 + l15
        kp += 1024;
        vp += 1024;

        #pragma unroll
        for (int f = 0; f < 4; ++f) {
            const f32x4 s0 = mfma16(kf0, qf[f], z);      // S rows f*16+l15, kv 4g+r
            const f32x4 s1 = mfma16(kf1, qf[f], z);      // kv 16+4g+r
            bfv8 pb;
            #pragma unroll
            for (int i = 0; i < 4; ++i) {
                pb[i]     = (__bf16)__builtin_amdgcn_exp2f(s0[i]);
                pb[4 + i] = (__bf16)__builtin_amdgcn_exp2f(s1[i]);
            }
            const bf16x8 pa = __builtin_bit_cast(bf16x8, pb);
            aO[f][0] = mfma16(pa, vf0, aO[f][0]);
            aO[f][1] = mfma16(pa, vf1, aO[f][1]);
            aD[f]    = mfma16(pa, onesf, aD[f]);
        }
    }

    // ---- merge the four quarters (plain addition; no max state) ------------
    if (widx != 0) {
        const int s = widx - 1;
        #pragma unroll
        for (int f = 0; f < 4; ++f) {
            *(f32x4*)&lacc[s][l15][f * 16 + 4 * g]      = aO[f][0];  // [col][row]
            *(f32x4*)&lacc[s][16 + l15][f * 16 + 4 * g] = aO[f][1];
            if (l15 == 0) {
                #pragma unroll
                for (int r = 0; r < 4; ++r)
                    lden[s][f * 16 + 4 * g + r] = aD[f][r];
            }
        }
    }
    __syncthreads();
    if (widx != 0) return;

    const int b = bh >> 2, h = bh & 3;
    #pragma unroll
    for (int f = 0; f < 4; ++f) {
        #pragma unroll
        for (int r = 0; r < 4; ++r) {
            const int row = f * 16 + 4 * g + r;
            const float rd = 1.0f / (aD[f][r] + lden[0][row] + lden[1][row] + lden[2][row]);
            const float o0 = aO[f][0][r] + lacc[0][l15][row]
                           + lacc[1][l15][row] + lacc[2][l15][row];
            const float o1 = aO[f][1][r] + lacc[0][16 + l15][row]
                           + lacc[1][16 + l15][row] + lacc[2][16 + l15][row];
            const size_t base = ((size_t)b * 4096 + q0 + row) * 128 + h * 32;
            Ob[base + l15]      = f2bf(o0 * rd);
            Ob[base + 16 + l15] = f2bf(o1 * rd);
        }
    }
}

// ---------------------------------------------------------------------------
// projo: out(b,c,n) = (O @ Wo^T + bo)^T via swapped MFMA (A=Wo rows, B=O rows)
__global__ __launch_bounds__(256) void k_projo(
    const unsigned short* __restrict__ Ob, const unsigned short* __restrict__ Wob,
    const float* __restrict__ bo, float* __restrict__ out)
{
    const int widx = threadIdx.x >> 6;
    const int lane = threadIdx.x & 63, g = lane >> 4, l15 = lane & 15;
    const int gt = blockIdx.x * 64 + widx * 16 + l15;  // token (col of D)
    const int b = gt >> 12, n = gt & 4095;

    bf16x8 of[4];
    #pragma unroll
    for (int kc = 0; kc < 4; ++kc)
        of[kc] = *(const bf16x8*)(Ob + (size_t)gt * 128 + kc * 32 + g * 8);

    #pragma unroll
    for (int ot = 0; ot < 8; ++ot) {
        f32x4 acc;
        #pragma unroll
        for (int r = 0; r < 4; ++r) acc[r] = bo[ot * 16 + 4 * g + r];
        #pragma unroll
        for (int kc = 0; kc < 4; ++kc) {
            bf16x8 wf = *(const bf16x8*)(Wob + (size_t)(ot * 16 + l15) * 128 + kc * 32 + g * 8);
            acc = mfma16(wf, of[kc], acc);
        }
        #pragma unroll
        for (int r = 0; r < 4; ++r)
            out[((size_t)b * 128 + ot * 16 + 4 * g + r) * 4096 + n] = acc[r];
    }
}

// ---------------------------------------------------------------------------
extern "C" void kernel_launch(void* const* d_in, const int* in_sizes, int n_in,
                              void* d_out, int out_size, void* d_ws, size_t ws_size,
                              hipStream_t stream)
{
    const float* x  = (const float*)d_in[0];
    const float* Wq = (const float*)d_in[1];
    const float* bq = (const float*)d_in[2];
    const float* Wk = (const float*)d_in[3];
    const float* bk = (const float*)d_in[4];
    const float* Wv = (const float*)d_in[5];
    const float* bv = (const float*)d_in[6];
    const float* Wo = (const float*)d_in[7];
    const float* bo = (const float*)d_in[8];
    float* out = (float*)d_out;

    char* ws = (char*)d_ws;
    unsigned short* t_bf = (unsigned short*)(ws);             //  8,388,608 B
    unsigned short* Wb   = (unsigned short*)(ws +  8388608);  //    131,072 B
    unsigned short* Qb   = (unsigned short*)(ws +  8519680);  //  8,388,608 B
    unsigned short* Kb   = (unsigned short*)(ws + 16908288);  //  8,388,608 B
    unsigned short* Vt   = (unsigned short*)(ws + 25296896);  //  8,388,608 B
    unsigned short* Ob   = (unsigned short*)(ws + 33685504);  //  8,388,608 B -> 42.1 MB total

    k_prep <<<dim3(1028),     dim3(256), 0, stream>>>(x, Wq, Wk, Wv, Wo, t_bf, Wb);
    k_proj3<<<dim3(512, 3),   dim3(256), 0, stream>>>(t_bf, Wb, bq, bk, bv, Qb, Kb, Vt);
    k_attn <<<dim3(2048),     dim3(256), 0, stream>>>(Qb, Kb, Vt, Ob);
    k_projo<<<dim3(512),      dim3(256), 0, stream>>>(Ob, Wb + 3 * 16384, bo, out);
}